// Round 2
// baseline (204.571 us; speedup 1.0000x reference)
//
#include <hip/hip_runtime.h>
#include <hip/hip_bf16.h>

typedef __bf16 bf16x8 __attribute__((ext_vector_type(8)));
typedef float  f32x4  __attribute__((ext_vector_type(4)));

#define DEV __device__ __forceinline__

DEV unsigned short f32_to_bf16(float f) {
  unsigned int u = __builtin_bit_cast(unsigned int, f);
  u += 0x7fffu + ((u >> 16) & 1u);
  return (unsigned short)(u >> 16);
}
DEV float bf16_to_f32(unsigned short h) {
  unsigned int u = ((unsigned int)h) << 16;
  return __builtin_bit_cast(float, u);
}
DEV bf16x8 load_frag(const void* p) {
  return __builtin_bit_cast(bf16x8, *(const uint4*)p);
}
DEV f32x4 mfma16(bf16x8 a, bf16x8 b, f32x4 c) {
  return __builtin_amdgcn_mfma_f32_16x16x32_bf16(a, b, c, 0, 0, 0);
}
DEV void async_cp16(void* lds_dst, const void* gsrc) {
  __builtin_amdgcn_global_load_lds(
      (const __attribute__((address_space(1))) void*)gsrc,
      (__attribute__((address_space(3))) void*)lds_dst,
      16, 0, 0);
}

// ---------------- convert x -> hi/lo bf16 ----------------
__global__ __launch_bounds__(256) void k_cvt_x(const float4* __restrict__ x,
                                               ushort4* __restrict__ xhi,
                                               ushort4* __restrict__ xlo) {
  int gid = blockIdx.x * 256 + threadIdx.x;   // 1048576 exact
  float4 v = x[gid];
  ushort4 h, l;
  h.x = f32_to_bf16(v.x); l.x = f32_to_bf16(v.x - bf16_to_f32(h.x));
  h.y = f32_to_bf16(v.y); l.y = f32_to_bf16(v.y - bf16_to_f32(h.y));
  h.z = f32_to_bf16(v.z); l.z = f32_to_bf16(v.z - bf16_to_f32(h.z));
  h.w = f32_to_bf16(v.w); l.w = f32_to_bf16(v.w - bf16_to_f32(h.w));
  xhi[gid] = h; xlo[gid] = l;
}

// ---------------- convert + transpose W: WT[n][k] hi/lo ----------------
__global__ __launch_bounds__(256) void k_cvt_w(
    const float* __restrict__ Wq, const float* __restrict__ Wk, const float* __restrict__ Wv,
    unsigned short* __restrict__ WqThi, unsigned short* __restrict__ WqTlo,
    unsigned short* __restrict__ WkThi, unsigned short* __restrict__ WkTlo,
    unsigned short* __restrict__ WvThi) {
  int z = blockIdx.z;
  const float* W = (z == 0) ? Wq : (z == 1) ? Wk : Wv;
  unsigned short* Ohi = (z == 0) ? WqThi : (z == 1) ? WkThi : WvThi;
  unsigned short* Olo = (z == 0) ? WqTlo : WkTlo;
  int t = blockIdx.x * 256 + threadIdx.x;  // 131072 exact
  int n = t & 255, k = t >> 8;
  float v = W[k * 256 + n];
  unsigned short h = f32_to_bf16(v);
  Ohi[n * 512 + k] = h;
  if (z < 2) Olo[n * 512 + k] = f32_to_bf16(v - bf16_to_f32(h));
}

// ---------------- projection GEMM: C[8192][256] = A[8192][512] * WT^T ----------------
// z=0: Q (3 passes hi*hi + lo*hi + hi*lo), z=1: K (3 passes), z=2: V (1 pass)
__global__ __launch_bounds__(256) void k_proj(
    const unsigned short* __restrict__ xhi, const unsigned short* __restrict__ xlo,
    const unsigned short* __restrict__ WqThi, const unsigned short* __restrict__ WqTlo,
    const unsigned short* __restrict__ WkThi, const unsigned short* __restrict__ WkTlo,
    const unsigned short* __restrict__ WvThi,
    unsigned short* __restrict__ Qhi, unsigned short* __restrict__ Qlo,
    unsigned short* __restrict__ Khi, unsigned short* __restrict__ Klo,
    unsigned short* __restrict__ Vtmp) {
  __shared__ __align__(16) unsigned char smem[24 * 1024];
  unsigned char* ldsA = smem;           // [128][64] bf16, src-swizzled
  unsigned char* ldsB = smem + 16384;   // [64][64] bf16

  const int z = blockIdx.z;
  const unsigned short* Bhi = (z == 0) ? WqThi : (z == 1) ? WkThi : WvThi;
  const unsigned short* Blo = (z == 0) ? WqTlo : WkTlo;
  unsigned short* Ohi = (z == 0) ? Qhi : (z == 1) ? Khi : Vtmp;
  unsigned short* Olo = (z == 0) ? Qlo : Klo;
  const int npass = (z == 2) ? 1 : 3;

  const int m0 = blockIdx.x * 128;
  const int n0 = blockIdx.y * 64;
  const int tid = threadIdx.x;
  const int w = tid >> 6, l = tid & 63;
  const int lr = l & 15, lg = l >> 4;
  const int wr = w >> 1, wc = w & 1;

  f32x4 acc[4][2] = {};

  for (int p = 0; p < npass; ++p) {
    const unsigned short* Ap = (p == 1) ? xlo : xhi;
    const unsigned short* Bp = (p == 2) ? Blo : Bhi;
    for (int kt = 0; kt < 8; ++kt) {
      const int k0 = kt * 64;
      __syncthreads();
      // stage A tile: 16 chunks of 1KB (8 rows x 128B each), wave does 4
#pragma unroll
      for (int ii = 0; ii < 4; ++ii) {
        int c = w * 4 + ii;
        int row = c * 8 + (l >> 3);
        const unsigned char* src = (const unsigned char*)Ap
            + (size_t)(m0 + row) * 1024 + k0 * 2
            + (((l & 7) * 16) ^ ((l >> 3) << 4));
        async_cp16(ldsA + c * 1024, src);
      }
      // stage B tile: 8 chunks, wave does 2
#pragma unroll
      for (int ii = 0; ii < 2; ++ii) {
        int c = w * 2 + ii;
        int row = c * 8 + (l >> 3);
        const unsigned char* src = (const unsigned char*)Bp
            + (size_t)(n0 + row) * 1024 + k0 * 2
            + (((l & 7) * 16) ^ ((l >> 3) << 4));
        async_cp16(ldsB + c * 1024, src);
      }
      __syncthreads();
#pragma unroll
      for (int ks = 0; ks < 2; ++ks) {
        bf16x8 af[4], bfr[2];
        const int colb = ks * 64 + lg * 16;
#pragma unroll
        for (int mb = 0; mb < 4; ++mb) {
          int row = wr * 64 + mb * 16 + lr;
          af[mb] = load_frag(ldsA + row * 128 + (colb ^ ((row & 7) << 4)));
        }
#pragma unroll
        for (int nb = 0; nb < 2; ++nb) {
          int row = wc * 32 + nb * 16 + lr;
          bfr[nb] = load_frag(ldsB + row * 128 + (colb ^ ((row & 7) << 4)));
        }
#pragma unroll
        for (int mb = 0; mb < 4; ++mb)
#pragma unroll
          for (int nb = 0; nb < 2; ++nb)
            acc[mb][nb] = mfma16(af[mb], bfr[nb], acc[mb][nb]);
      }
    }
  }

  const bool wlo = (z != 2);
#pragma unroll
  for (int mb = 0; mb < 4; ++mb)
#pragma unroll
    for (int nb = 0; nb < 2; ++nb)
#pragma unroll
      for (int j = 0; j < 4; ++j) {
        int row = m0 + wr * 64 + mb * 16 + lg * 4 + j;
        int col = n0 + wc * 32 + nb * 16 + lr;
        float v = acc[mb][nb][j];
        unsigned short h = f32_to_bf16(v);
        Ohi[(size_t)row * 256 + col] = h;
        if (wlo) Olo[(size_t)row * 256 + col] = f32_to_bf16(v - bf16_to_f32(h));
      }
}

// ---------------- V transpose: Vt[b][u][t] = V[b][t][u] ----------------
__global__ __launch_bounds__(256) void k_vtrans(const unsigned short* __restrict__ V,
                                                unsigned short* __restrict__ Vt) {
  __shared__ unsigned short tile[64][65];
  int t0 = blockIdx.x * 64, u0 = blockIdx.y * 64, b = blockIdx.z;
  int tid = threadIdx.x;
#pragma unroll
  for (int i = 0; i < 16; ++i) {
    int idx = tid + i * 256;
    int r = idx >> 6, c = idx & 63;
    tile[r][c] = V[(size_t)(b * 2048 + t0 + r) * 256 + u0 + c];
  }
  __syncthreads();
#pragma unroll
  for (int i = 0; i < 16; ++i) {
    int idx = tid + i * 256;
    int ur = idx >> 6, tc = idx & 63;
    Vt[(size_t)(b * 256 + u0 + ur) * 2048 + t0 + tc] = tile[tc][ur];
  }
}

// ---------------- flash attention with 4-way KV split ----------------
// 512 blocks: logical idx -> (chunk = b*4+qq, qt); QBLK=64 (wave = 16 rows), KVBLK=32
__global__ __launch_bounds__(256, 2) void k_attn(
    const unsigned short* __restrict__ Qhi, const unsigned short* __restrict__ Qlo,
    const unsigned short* __restrict__ Khi, const unsigned short* __restrict__ Klo,
    const unsigned short* __restrict__ Vt,
    float* __restrict__ pO, float* __restrict__ pm, float* __restrict__ pl) {
  __shared__ __align__(16) unsigned char smem[53248];
  unsigned char* ldsKh = smem;            // [32][256] bf16 (16KB)
  unsigned char* ldsKl = smem + 16384;    // [32][256]
  unsigned char* ldsV  = smem + 32768;    // [256][32]  (u-major, 64B rows)
  unsigned char* ldsP  = smem + 49152;    // 4 waves x [16][32] (1KB each)

  const int phys = blockIdx.x;
  const int idx  = (phys & 7) * 64 + (phys >> 3);   // bijective XCD swizzle
  const int chunk = idx >> 5, qt = idx & 31;
  const int b = chunk >> 2, qq = chunk & 3;
  const int q0 = qt * 64;
  const int tbase = qq * 512;

  const int tid = threadIdx.x, w = tid >> 6, l = tid & 63;
  const int lr = l & 15, lg = l >> 4;

  // Q fragments resident in registers: 8 k-steps x (hi, lo)
  bf16x8 qh[8], ql[8];
  {
    const size_t qrow = (size_t)(b * 2048 + q0 + w * 16 + lr) * 256;
#pragma unroll
    for (int ks = 0; ks < 8; ++ks) {
      int u0 = ks * 32 + lg * 8;
      qh[ks] = load_frag(Qhi + qrow + u0);
      ql[ks] = load_frag(Qlo + qrow + u0);
    }
  }

  f32x4 acc[16] = {};
  float mrun[4], lrun[4];
#pragma unroll
  for (int j = 0; j < 4; ++j) { mrun[j] = -__builtin_inff(); lrun[j] = 0.f; }

  const unsigned char* Khb = (const unsigned char*)Khi + (size_t)b * 2048 * 512;
  const unsigned char* Klb = (const unsigned char*)Klo + (size_t)b * 2048 * 512;
  const unsigned char* Vtb = (const unsigned char*)Vt + (size_t)b * 256 * 4096;

  for (int it = 0; it < 16; ++it) {
    const int t0 = tbase + it * 32;
    __syncthreads();
    // stage Khi(16) + Klo(16) + V(16) 1KB chunks; wave does 12 (uniform branch)
#pragma unroll
    for (int ii = 0; ii < 12; ++ii) {
      int s = w * 12 + ii;
      if (s < 32) {
        int c = s & 15;
        int row = c * 2 + (l >> 5);
        int colb = ((l & 31) * 16) ^ ((row & 7) << 4);
        const unsigned char* base = (s < 16) ? Khb : Klb;
        unsigned char* dst = ((s < 16) ? ldsKh : ldsKl) + c * 1024;
        async_cp16(dst, base + (size_t)(t0 + row) * 512 + colb);
      } else {
        int c = s - 32;
        int row = c * 16 + (l >> 2);    // u
        int colb = ((l & 3) * 16) ^ (((row >> 1) & 3) << 4);
        async_cp16(ldsV + c * 1024, Vtb + (size_t)row * 4096 + t0 * 2 + colb);
      }
    }
    __syncthreads();

    // S = Q K^T  (3-pass split, 6 independent accumulation chains)
    f32x4 sA0 = {}, sA1 = {}, sB0 = {}, sB1 = {}, sC0 = {}, sC1 = {};
#pragma unroll
    for (int ks = 0; ks < 8; ++ks) {
      int colb = ks * 64 + lg * 16;
      int sw = (lr & 7) << 4;
      bf16x8 kh0 = load_frag(ldsKh + lr * 512 + (colb ^ sw));
      bf16x8 kh1 = load_frag(ldsKh + (16 + lr) * 512 + (colb ^ sw));
      bf16x8 kl0 = load_frag(ldsKl + lr * 512 + (colb ^ sw));
      bf16x8 kl1 = load_frag(ldsKl + (16 + lr) * 512 + (colb ^ sw));
      sA0 = mfma16(qh[ks], kh0, sA0); sA1 = mfma16(qh[ks], kh1, sA1);
      sB0 = mfma16(ql[ks], kh0, sB0); sB1 = mfma16(ql[ks], kh1, sB1);
      sC0 = mfma16(qh[ks], kl0, sC0); sC1 = mfma16(qh[ks], kl1, sC1);
    }
    f32x4 s0 = sA0 + sB0 + sC0;
    f32x4 s1 = sA1 + sB1 + sC1;

    // online softmax: lane holds rows lg*4+j, col lr (+16)
    float al[4];
#pragma unroll
    for (int j = 0; j < 4; ++j) {
      float mt = fmaxf(s0[j], s1[j]);
#pragma unroll
      for (int msk = 1; msk < 16; msk <<= 1)
        mt = fmaxf(mt, __shfl_xor(mt, msk, 64));
      float mn = fmaxf(mrun[j], mt);
      al[j] = __expf(mrun[j] - mn);
      mrun[j] = mn;
      float p0 = __expf(s0[j] - mn);
      float p1 = __expf(s1[j] - mn);
      s0[j] = p0; s1[j] = p1;
      float rs = p0 + p1;
#pragma unroll
      for (int msk = 1; msk < 16; msk <<= 1)
        rs += __shfl_xor(rs, msk, 64);
      lrun[j] = al[j] * lrun[j] + rs;
    }
#pragma unroll
    for (int nb = 0; nb < 16; ++nb) {
      f32x4 a = acc[nb];
      a[0] *= al[0]; a[1] *= al[1]; a[2] *= al[2]; a[3] *= al[3];
      acc[nb] = a;
    }

    // P -> bf16 into per-wave LDS [16][32] (swizzled)
    unsigned char* Pw = ldsP + w * 1024;
#pragma unroll
    for (int j = 0; j < 4; ++j) {
      int rowp = lg * 4 + j;
      int sw = ((rowp >> 1) & 3) << 4;
      *(unsigned short*)(Pw + rowp * 64 + ((lr * 2) ^ sw)) = f32_to_bf16(s0[j]);
      *(unsigned short*)(Pw + rowp * 64 + (((16 + lr) * 2) ^ sw)) = f32_to_bf16(s1[j]);
    }
    __syncthreads();   // order P writes before cross-lane P reads (safe round-1 choice)

    // O += P V  (A = P[q][t], B from Vt[u][t])
    bf16x8 pf = load_frag(Pw + lr * 64 + ((lg * 16) ^ (((lr >> 1) & 3) << 4)));
#pragma unroll
    for (int nb = 0; nb < 16; ++nb) {
      int ru = nb * 16 + lr;
      bf16x8 vf = load_frag(ldsV + ru * 64 + ((lg * 16) ^ (((ru >> 1) & 3) << 4)));
      acc[nb] = mfma16(pf, vf, acc[nb]);
    }
  }

  // write partials
  const size_t prow = (size_t)idx * 64 + w * 16;
#pragma unroll
  for (int nb = 0; nb < 16; ++nb)
#pragma unroll
    for (int j = 0; j < 4; ++j)
      pO[(prow + lg * 4 + j) * 256 + nb * 16 + lr] = acc[nb][j];
  if (lr == 0) {
#pragma unroll
    for (int j = 0; j < 4; ++j) {
      pm[prow + lg * 4 + j] = mrun[j];
      pl[prow + lg * 4 + j] = lrun[j];
    }
  }
}

// ---------------- combine the 4 KV-split partials ----------------
__global__ __launch_bounds__(256) void k_combine(
    const float* __restrict__ pO, const float* __restrict__ pm, const float* __restrict__ pl,
    float* __restrict__ out) {
  int gid = blockIdx.x * 256 + threadIdx.x;  // 8192*64 exact (f32x4 per thread)
  int gr = gid >> 6, uq = gid & 63;
  int b = gr >> 11, r = gr & 2047;
  int qt = r >> 6, rr = r & 63;
  float mv[4];
#pragma unroll
  for (int q = 0; q < 4; ++q)
    mv[q] = pm[(size_t)((b * 4 + q) * 32 + qt) * 64 + rr];
  float m = fmaxf(fmaxf(mv[0], mv[1]), fmaxf(mv[2], mv[3]));
  float lsum = 0.f, wq[4];
#pragma unroll
  for (int q = 0; q < 4; ++q) {
    wq[q] = __expf(mv[q] - m);
    lsum += wq[q] * pl[(size_t)((b * 4 + q) * 32 + qt) * 64 + rr];
  }
  f32x4 o = {};
#pragma unroll
  for (int q = 0; q < 4; ++q) {
    const f32x4 v = *(const f32x4*)(pO + ((size_t)((b * 4 + q) * 32 + qt) * 64 + rr) * 256 + uq * 4);
    o += v * wq[q];
  }
  f32x4 res = o * (1.0f / lsum);
  *(f32x4*)(out + (size_t)gr * 256 + uq * 4) = res;
}

extern "C" void kernel_launch(void* const* d_in, const int* in_sizes, int n_in,
                              void* d_out, int out_size, void* d_ws, size_t ws_size,
                              hipStream_t stream) {
  const float* x  = (const float*)d_in[0];
  const float* Wq = (const float*)d_in[1];
  const float* Wk = (const float*)d_in[2];
  const float* Wv = (const float*)d_in[3];
  float* out = (float*)d_out;

  unsigned char* ws = (unsigned char*)d_ws;
  unsigned short* xhi   = (unsigned short*)(ws + 0);          // 8.39 MB
  unsigned short* xlo   = (unsigned short*)(ws + 8388608);
  unsigned short* WqThi = (unsigned short*)(ws + 16777216);   // 256KB each
  unsigned short* WqTlo = (unsigned short*)(ws + 17039360);
  unsigned short* WkThi = (unsigned short*)(ws + 17301504);
  unsigned short* WkTlo = (unsigned short*)(ws + 17563648);
  unsigned short* WvThi = (unsigned short*)(ws + 17825792);
  unsigned short* Qhi   = (unsigned short*)(ws + 18087936);   // 4.19 MB each
  unsigned short* Qlo   = (unsigned short*)(ws + 22282240);
  unsigned short* Khi   = (unsigned short*)(ws + 26476544);
  unsigned short* Klo   = (unsigned short*)(ws + 30670848);
  unsigned short* Vtmp  = (unsigned short*)(ws + 34865152);
  unsigned short* Vt    = (unsigned short*)(ws + 39059456);
  float*  pO    = (float*)(ws + 43253760);                    // 33.55 MB
  float*  pm    = (float*)(ws + 76808192);
  float*  pl    = (float*)(ws + 76939264);                    // end ~77.07 MB

  k_cvt_x<<<4096, 256, 0, stream>>>((const float4*)x, (ushort4*)xhi, (ushort4*)xlo);
  k_cvt_w<<<dim3(512, 1, 3), 256, 0, stream>>>(Wq, Wk, Wv, WqThi, WqTlo, WkThi, WkTlo, WvThi);
  k_proj<<<dim3(64, 4, 3), 256, 0, stream>>>(xhi, xlo, WqThi, WqTlo, WkThi, WkTlo, WvThi,
                                             Qhi, Qlo, Khi, Klo, Vtmp);
  k_vtrans<<<dim3(32, 4, 4), 256, 0, stream>>>(Vtmp, Vt);
  k_attn<<<512, 256, 0, stream>>>(Qhi, Qlo, Khi, Klo, Vt, pO, pm, pl);
  k_combine<<<2048, 256, 0, stream>>>(pO, pm, pl, out);
}

// Round 10
// 127.568 us; speedup vs baseline: 1.6036x; 1.6036x over previous
//
#include <hip/hip_runtime.h>
#include <hip/hip_bf16.h>

typedef _Float16 f16;
typedef _Float16 f16x8 __attribute__((ext_vector_type(8)));
typedef _Float16 f16x4 __attribute__((ext_vector_type(4)));
typedef float    f32x4 __attribute__((ext_vector_type(4)));

#define DEV __device__ __forceinline__

DEV f16x8 load16(const void* p) {
  return __builtin_bit_cast(f16x8, *(const uint4*)p);
}
DEV f32x4 mfma(f16x8 a, f16x8 b, f32x4 c) {
  return __builtin_amdgcn_mfma_f32_16x16x32_f16(a, b, c, 0, 0, 0);
}
DEV void async_cp16(void* lds_dst, const void* gsrc) {
  __builtin_amdgcn_global_load_lds(
      (const __attribute__((address_space(1))) void*)gsrc,
      (__attribute__((address_space(3))) void*)lds_dst,
      16, 0, 0);
}
DEV int pk2(float a, float b) {
  return __builtin_bit_cast(int, __builtin_amdgcn_cvt_pkrtz(a, b));
}
DEV int bperm(int lane_times4, int v) {
  return __builtin_amdgcn_ds_bpermute(lane_times4, v);
}

// ---------------- convert x -> f16 ----------------
__global__ __launch_bounds__(256) void k_cvt_x(const float4* __restrict__ x,
                                               f16x4* __restrict__ xf) {
  int gid = blockIdx.x * 256 + threadIdx.x;   // 1048576 exact
  float4 v = x[gid];
  f16x4 h = {(f16)v.x, (f16)v.y, (f16)v.z, (f16)v.w};
  xf[gid] = h;
}

// ---------------- convert + transpose W: WT[n][k] f16 ----------------
__global__ __launch_bounds__(256) void k_cvt_w(
    const float* __restrict__ Wq, const float* __restrict__ Wk, const float* __restrict__ Wv,
    f16* __restrict__ WqT, f16* __restrict__ WkT, f16* __restrict__ WvT) {
  int z = blockIdx.z;
  const float* W = (z == 0) ? Wq : (z == 1) ? Wk : Wv;
  f16* O = (z == 0) ? WqT : (z == 1) ? WkT : WvT;
  int t = blockIdx.x * 256 + threadIdx.x;  // 131072 exact
  int n = t & 255, k = t >> 8;
  O[n * 512 + k] = (f16)W[k * 256 + n];
}

// ---------------- projection GEMM (f16 single chain, double-buffered) ----------------
// z=0: Q, z=1: K, z=2: V emitted TRANSPOSED as Vt[b][u][t]
__global__ __launch_bounds__(256, 3) void k_proj(
    const f16* __restrict__ xf,
    const f16* __restrict__ WqT, const f16* __restrict__ WkT, const f16* __restrict__ WvT,
    f16* __restrict__ Qf, f16* __restrict__ Kf, f16* __restrict__ Vt) {
  __shared__ __align__(16) unsigned char smem[49152];  // 2 x (A 16KB + B 8KB)

  const int z = blockIdx.z;
  const f16* Bw = (z == 0) ? WqT : (z == 1) ? WkT : WvT;
  const int m0 = blockIdx.x * 128;
  const int n0 = blockIdx.y * 64;
  const int tid = threadIdx.x;
  const int w = tid >> 6, l = tid & 63;
  const int lr = l & 15, lg = l >> 4;
  const int wr = w >> 1, wc = w & 1;

  f32x4 acc[4][2] = {};

  const unsigned char* Ab = (const unsigned char*)xf;
  const unsigned char* Bb = (const unsigned char*)Bw;

  auto STAGE = [&](int kt, int bufo) {
    const int k0b = kt * 128;  // 64 f16 = 128B per k-block
#pragma unroll
    for (int ii = 0; ii < 4; ++ii) {           // A: 16 chunks, wave does 4
      int c = w * 4 + ii;
      int row = c * 8 + (l >> 3);
      async_cp16(smem + bufo + c * 1024,
                 Ab + (size_t)(m0 + row) * 1024 + k0b + (((l & 7) * 16) ^ ((l >> 3) << 4)));
    }
#pragma unroll
    for (int ii = 0; ii < 2; ++ii) {           // B: 8 chunks, wave does 2
      int c = w * 2 + ii;
      int row = c * 8 + (l >> 3);
      async_cp16(smem + bufo + 16384 + c * 1024,
                 Bb + (size_t)(n0 + row) * 1024 + k0b + (((l & 7) * 16) ^ ((l >> 3) << 4)));
    }
  };

  STAGE(0, 0);
  __syncthreads();

  for (int kt = 0; kt < 8; ++kt) {
    const int cur = (kt & 1) * 24576;
    if (kt < 7) STAGE(kt + 1, cur ^ 24576);
    const unsigned char* ldsA = smem + cur;
    const unsigned char* ldsB = smem + cur + 16384;
#pragma unroll
    for (int ks = 0; ks < 2; ++ks) {
      f16x8 af[4], bf[2];
      const int colb = ks * 64 + lg * 16;
#pragma unroll
      for (int mb = 0; mb < 4; ++mb) {
        int row = wr * 64 + mb * 16 + lr;
        af[mb] = load16(ldsA + row * 128 + (colb ^ ((row & 7) << 4)));
      }
#pragma unroll
      for (int nb = 0; nb < 2; ++nb) {
        int row = wc * 32 + nb * 16 + lr;
        bf[nb] = load16(ldsB + row * 128 + (colb ^ ((row & 7) << 4)));
      }
      if (z != 2) {
#pragma unroll
        for (int mb = 0; mb < 4; ++mb)
#pragma unroll
          for (int nb = 0; nb < 2; ++nb)
            acc[mb][nb] = mfma(af[mb], bf[nb], acc[mb][nb]);
      } else {
#pragma unroll
        for (int mb = 0; mb < 4; ++mb)
#pragma unroll
          for (int nb = 0; nb < 2; ++nb)
            acc[mb][nb] = mfma(bf[nb], af[mb], acc[mb][nb]);
      }
    }
    __syncthreads();
  }

  if (z != 2) {
    f16* O = (z == 0) ? Qf : Kf;
#pragma unroll
    for (int mb = 0; mb < 4; ++mb)
#pragma unroll
      for (int nb = 0; nb < 2; ++nb)
#pragma unroll
        for (int j = 0; j < 4; ++j) {
          int row = m0 + wr * 64 + mb * 16 + lg * 4 + j;
          int col = n0 + wc * 32 + nb * 16 + lr;
          O[(size_t)row * 256 + col] = (f16)acc[mb][nb][j];
        }
  } else {
    // acc holds D[m=u][n=t]; emit Vt[b][u][t]
    const int bb = m0 >> 11;
    const int tl0 = m0 & 2047;
#pragma unroll
    for (int mb = 0; mb < 4; ++mb)
#pragma unroll
      for (int nb = 0; nb < 2; ++nb)
#pragma unroll
        for (int j = 0; j < 4; ++j) {
          int u  = n0 + wc * 32 + nb * 16 + lg * 4 + j;
          int tg = tl0 + wr * 64 + mb * 16 + lr;
          Vt[((size_t)bb * 256 + u) * 2048 + tg] = (f16)acc[mb][nb][j];
        }
  }
}

// ---------------- flash attention, f16, swapped-QK, pipelined ----------------
// 512 blocks: idx -> (chunk = b*4+qq, qt); QBLK=64 (4 waves x 16 q-rows), KVBLK=32
__global__ __launch_bounds__(256, 2) void k_attn(
    const f16* __restrict__ Qf, const f16* __restrict__ Kf, const f16* __restrict__ Vt,
    f16* __restrict__ pO, float* __restrict__ pm, float* __restrict__ pl) {
  __shared__ __align__(16) unsigned char smem[65536];  // 2 x (K 16KB + V 16KB)

  const int phys = blockIdx.x;
  const int idx  = (phys & 7) * 64 + (phys >> 3);   // bijective XCD swizzle (512 = 8*64)
  const int chunk = idx >> 5, qt = idx & 31;
  const int b = chunk >> 2, qq = chunk & 3;
  const int q0 = qt * 64;
  const int tbase = qq * 512;

  const int tid = threadIdx.x, w = tid >> 6, l = tid & 63;
  const int lr = l & 15, lg = l >> 4;

  // Q fragments resident: B-operand of swapped QK (lane: Q[q = w*16+lr][u = ks*32+lg*8..])
  f16x8 qh[8];
  {
    const f16* qrow = Qf + (size_t)(b * 2048 + q0 + w * 16 + lr) * 256;
#pragma unroll
    for (int ks = 0; ks < 8; ++ks) qh[ks] = load16(qrow + ks * 32 + lg * 8);
  }

  f32x4 acc[16] = {};
  float mrun = -__builtin_inff(), lrun = 0.f;   // stats for q = lr (uniform over lg)

  const unsigned char* Kb = (const unsigned char*)Kf + (size_t)b * 2048 * 512;
  const unsigned char* Vb = (const unsigned char*)Vt + (size_t)b * 256 * 4096;

  auto STAGE = [&](int it, int bufo) {
    const int t0 = tbase + it * 32;
#pragma unroll
    for (int ii = 0; ii < 8; ++ii) {
      int s = w * 8 + ii;
      if (s < 16) {                       // K tile [32][256] f16, 16 x 1KB (2 rows each)
        int row = s * 2 + (l >> 5);
        async_cp16(smem + bufo + s * 1024,
                   Kb + (size_t)(t0 + row) * 512 + (((l & 31) * 16) ^ ((row & 7) << 4)));
      } else {                            // V tile [256][32] f16, 16 x 1KB (16 u-rows each)
        int c = s - 16;
        int row = c * 16 + (l >> 2);
        async_cp16(smem + bufo + 16384 + c * 1024,
                   Vb + (size_t)row * 4096 + t0 * 2 + (((l & 3) * 16) ^ (((row >> 1) & 3) << 4)));
      }
    }
  };

  STAGE(0, 0);
  __syncthreads();

  for (int it = 0; it < 16; ++it) {
    const int cur = (it & 1) << 15;
    if (it < 15) STAGE(it + 1, cur ^ 32768);
    const unsigned char* ldsK = smem + cur;
    const unsigned char* ldsV = smem + cur + 16384;

    // S = K Q^T (swapped): lane holds S[t = lg*4+j (+16)][q = lr]
    f32x4 s0 = {}, s1 = {};
    const int sw = (lr & 7) << 4;
#pragma unroll
    for (int ks = 0; ks < 8; ++ks) {
      const int colb = ks * 64 + lg * 16;
      f16x8 k0 = load16(ldsK + lr * 512 + (colb ^ sw));
      f16x8 k1 = load16(ldsK + (16 + lr) * 512 + (colb ^ sw));
      s0 = mfma(k0, qh[ks], s0);
      s1 = mfma(k1, qh[ks], s1);
    }

    // in-register online softmax (8 vals/lane), defer-max THR=5
    float mt = fmaxf(fmaxf(fmaxf(s0[0], s0[1]), fmaxf(s0[2], s0[3])),
                     fmaxf(fmaxf(s1[0], s1[1]), fmaxf(s1[2], s1[3])));
    mt = fmaxf(mt, __shfl_xor(mt, 16, 64));
    mt = fmaxf(mt, __shfl_xor(mt, 32, 64));
    const bool need = !__all(mt <= mrun + 5.f);
    float al = 1.f;
    if (need) {                  // wave-uniform branch (from __all)
      float mn = fmaxf(mrun, mt);
      al = __expf(mrun - mn);
      mrun = mn;
    }
    float p0[4], p1[4];
#pragma unroll
    for (int j = 0; j < 4; ++j) {
      p0[j] = __expf(s0[j] - mrun);
      p1[j] = __expf(s1[j] - mrun);
    }
    float rs = (p0[0] + p0[1]) + (p0[2] + p0[3]) + (p1[0] + p1[1]) + (p1[2] + p1[3]);
    rs += __shfl_xor(rs, 16, 64);
    rs += __shfl_xor(rs, 32, 64);
    lrun = al * lrun + rs;

    if (need) {     // rescale acc: gather al for q = lg*4+j from lane (lg*4+j) (active)
      float alj[4];
#pragma unroll
      for (int j = 0; j < 4; ++j)
        alj[j] = __builtin_bit_cast(float, bperm((lg * 4 + j) * 4, __builtin_bit_cast(int, al)));
#pragma unroll
      for (int nb = 0; nb < 16; ++nb) {
        f32x4 a = acc[nb];
        a[0] *= alj[0]; a[1] *= alj[1]; a[2] *= alj[2]; a[3] *= alj[3];
        acc[nb] = a;
      }
    }

    // P redistribution to PV A-frag via bpermute.
    // Target lane (LR,LG) needs P[q=LR][t=LG*8 .. +8).
    // FIX (round-3 bug): all 8 bpermutes issued at FULL EXEC (straight-line);
    // lane-divergent selection happens on the landed values (v_cndmask), never
    // on which convergent ds_bpermute executes.
    int a0 = pk2(p0[0], p0[1]), a1 = pk2(p0[2], p0[3]);
    int b0 = pk2(p1[0], p1[1]), b1 = pk2(p1[2], p1[3]);
    const int srcA = (lr + ((lg & 1) ? 32 : 0)) * 4;
    const int srcB = srcA + 64;
    int ta0 = bperm(srcA, a0), ta1 = bperm(srcA, a1);
    int tb0 = bperm(srcA, b0), tb1 = bperm(srcA, b1);
    int ua0 = bperm(srcB, a0), ua1 = bperm(srcB, a1);
    int ub0 = bperm(srcB, b0), ub1 = bperm(srcB, b1);
    const bool useb = lg >= 2;
    int d0 = useb ? tb0 : ta0;
    int d1 = useb ? tb1 : ta1;
    int d2 = useb ? ub0 : ua0;
    int d3 = useb ? ub1 : ua1;
    int4 dv = {d0, d1, d2, d3};
    f16x8 pa = __builtin_bit_cast(f16x8, dv);

    // O += P V
#pragma unroll
    for (int nb = 0; nb < 16; ++nb) {
      int ru = nb * 16 + lr;
      f16x8 vf = load16(ldsV + ru * 64 + ((lg * 16) ^ (((ru >> 1) & 3) << 4)));
      acc[nb] = mfma(pa, vf, acc[nb]);
    }

    __syncthreads();   // drains prefetch vmcnt; buf[cur] free; next tile ready
  }

  // write partials (pO f16)
  const size_t prow = (size_t)idx * 64 + w * 16;
#pragma unroll
  for (int nb = 0; nb < 16; ++nb)
#pragma unroll
    for (int j = 0; j < 4; ++j)
      pO[(prow + lg * 4 + j) * 256 + nb * 16 + lr] = (f16)acc[nb][j];
  if (l < 16) {
    pm[prow + lr] = mrun;
    pl[prow + lr] = lrun;
  }
}

// ---------------- combine the 4 KV-split partials ----------------
__global__ __launch_bounds__(256) void k_combine(
    const f16* __restrict__ pO, const float* __restrict__ pm, const float* __restrict__ pl,
    float* __restrict__ out) {
  int gid = blockIdx.x * 256 + threadIdx.x;  // 8192*64 exact (4 u-values per thread)
  int gr = gid >> 6, uq = gid & 63;
  int b = gr >> 11, r = gr & 2047;
  int qt = r >> 6, rr = r & 63;
  float mv[4];
#pragma unroll
  for (int q = 0; q < 4; ++q)
    mv[q] = pm[(size_t)((b * 4 + q) * 32 + qt) * 64 + rr];
  float m = fmaxf(fmaxf(mv[0], mv[1]), fmaxf(mv[2], mv[3]));
  float lsum = 0.f, wq[4];
#pragma unroll
  for (int q = 0; q < 4; ++q) {
    wq[q] = __expf(mv[q] - m);
    lsum += wq[q] * pl[(size_t)((b * 4 + q) * 32 + qt) * 64 + rr];
  }
  f32x4 o = {};
#pragma unroll
  for (int q = 0; q < 4; ++q) {
    const f16x4 hv = *(const f16x4*)(pO + ((size_t)((b * 4 + q) * 32 + qt) * 64 + rr) * 256 + uq * 4);
    f32x4 v = {(float)hv[0], (float)hv[1], (float)hv[2], (float)hv[3]};
    o += v * wq[q];
  }
  f32x4 res = o * (1.0f / lsum);
  *(f32x4*)(out + (size_t)gr * 256 + uq * 4) = res;
}

extern "C" void kernel_launch(void* const* d_in, const int* in_sizes, int n_in,
                              void* d_out, int out_size, void* d_ws, size_t ws_size,
                              hipStream_t stream) {
  const float* x  = (const float*)d_in[0];
  const float* Wq = (const float*)d_in[1];
  const float* Wk = (const float*)d_in[2];
  const float* Wv = (const float*)d_in[3];
  float* out = (float*)d_out;

  unsigned char* ws = (unsigned char*)d_ws;
  f16*   xf  = (f16*)(ws + 0);             // 8.39 MB
  f16*   WqT = (f16*)(ws + 8388608);       // 256 KB
  f16*   WkT = (f16*)(ws + 8650752);
  f16*   WvT = (f16*)(ws + 8912896);
  f16*   Qf  = (f16*)(ws + 9175040);       // 4.19 MB
  f16*   Kf  = (f16*)(ws + 13369344);
  f16*   Vt  = (f16*)(ws + 17563648);
  f16*   pO  = (f16*)(ws + 21757952);      // 16.78 MB
  float* pm  = (float*)(ws + 38535168);    // 128 KB
  float* pl  = (float*)(ws + 38666240);    // end ~38.8 MB

  k_cvt_x<<<4096, 256, 0, stream>>>((const float4*)x, (f16x4*)xf);
  k_cvt_w<<<dim3(512, 1, 3), 256, 0, stream>>>(Wq, Wk, Wv, WqT, WkT, WvT);
  k_proj<<<dim3(64, 4, 3), 256, 0, stream>>>(xf, WqT, WkT, WvT, Qf, Kf, Vt);
  k_attn<<<512, 256, 0, stream>>>(Qf, Kf, Vt, pO, pm, pl);
  k_combine<<<2048, 256, 0, stream>>>(pO, pm, pl, out);
}